// Round 8
// baseline (120.037 us; speedup 1.0000x reference)
//
#include <hip/hip_runtime.h>
#include <math.h>

#define NQ 10
#define NSTATE 1024
#define WW 113
#define BB 16
#define CC 22
#define NF 8
#define FDIM 352   // CC*NF*2
#define NS (BB*WW) // 1808
#define NGATE 23

__device__ __forceinline__ constexpr int SLOT(int j) { return j ^ ((j >> 5) & 31); }
// SLOT(base | (1<<p)) == SLOT(base) ^ DD(p) when bit p of base is 0
__device__ __forceinline__ constexpr int DD(int p) { return (1 << p) | (p >= 5 ? (1 << (p - 5)) : 0); }

__device__ __forceinline__ int ins0(int j, int p) {
    return ((j >> p) << (p + 1)) | (j & ((1 << p) - 1));
}

__device__ __forceinline__ float2 cmulf(float2 a, float2 b) {
    return make_float2(a.x*b.x - a.y*b.y, a.x*b.y + a.y*b.x);
}
__device__ __forceinline__ void cmacf(float2& acc, float2 c, float2 v) {
    acc.x = fmaf(c.x, v.x, acc.x); acc.x = fmaf(-c.y, v.y, acc.x);
    acc.y = fmaf(c.x, v.y, acc.y); acc.y = fmaf(c.y, v.x, acc.y);
}

// ---------------- gate table (static circuit structure) -------------------
__constant__ int G_KIND[NGATE]  = {0,0,0,0,0, 0,0,0,0, 1,1,1,1,1, 0,0,0,0, 1,1, 0,0, 1};
__constant__ int G_LAYER[NGATE] = {0,0,0,0,0, 0,0,0,0, 0,0,0,0,0, 1,1,1,1, 1,1, 2,2, 2};
__constant__ int G_IA[NGATE]    = {0,2,4,6,8, 1,3,5,7, 0,1,2,3,4, 0,2,1,3, 0,1, 0,1, 0};

__device__ __forceinline__ void u3mat(float2* U, float th, float ph, float lm) {
    float ct, st, cp, sp, cl, sl;
    sincosf(th * 0.5f, &st, &ct);
    sincosf(ph, &sp, &cp);
    sincosf(lm, &sl, &cl);
    U[0] = make_float2(ct, 0.f);
    U[1] = make_float2(-cl * st, -sl * st);
    U[2] = make_float2(cp * st, sp * st);
    U[3] = make_float2((cp * cl - sp * sl) * ct, (sp * cl + cp * sl) * ct);
}

// prep: one thread per matrix ELEMENT (23 gates x 16 elems = 368 threads)
__global__ __launch_bounds__(384) void prep_kernel(
    const float* __restrict__ conv,   // (3,10,15)
    const float* __restrict__ pool,   // (3,5,3)
    const float* __restrict__ aggw,   // (113,)
    float2* __restrict__ mats,        // (23,16)
    float* __restrict__ wts,          // (113,)
    float* __restrict__ out)          // (16,) -> zeroed
{
    const int t = threadIdx.x;

    if (t < 64) {  // wave 0: softmax over aggw
        float a0 = (t < WW) ? aggw[t] : -1e30f;
        float a1 = (t + 64 < WW) ? aggw[t + 64] : -1e30f;
        float mx = fmaxf(a0, a1);
        for (int off = 32; off > 0; off >>= 1) mx = fmaxf(mx, __shfl_xor(mx, off));
        float e0 = (t < WW) ? expf(a0 - mx) : 0.f;
        float e1 = (t + 64 < WW) ? expf(a1 - mx) : 0.f;
        float es = e0 + e1;
        for (int off = 32; off > 0; off >>= 1) es += __shfl_xor(es, off);
        float inv = 1.0f / es;
        if (t < WW) wts[t] = e0 * inv;
        if (t + 64 < WW) wts[t + 64] = e1 * inv;
        if (t < BB) out[t] = 0.f;
    }

    if (t >= NGATE * 16) return;
    const int g = t >> 4, k = t & 15;
    const int i = k >> 2, j = k & 3;
    const int kind = G_KIND[g], layer = G_LAYER[g], ia = G_IA[g];
    float2 F;
    if (kind == 1) {
        const float* pp = pool + layer * 15 + ia * 3;
        if (i < 2 || j < 2) {
            F = (i == j) ? make_float2(1.f, 0.f) : make_float2(0.f, 0.f);
        } else {
            float2 U[4];
            u3mat(U, pp[0], pp[1], pp[2]);
            F = U[(i - 2) * 2 + (j - 2)];
        }
    } else {
        const float* wp = conv + layer * 150;
        float2 Uw0[4], Un0[4], Uw1[4], Un1[4];
        u3mat(Uw0, wp[ia*15+0],  wp[ia*15+1],  wp[ia*15+2]);
        u3mat(Un0, wp[(ia+1)*15+3],  wp[(ia+1)*15+4],  wp[(ia+1)*15+5]);
        u3mat(Uw1, wp[ia*15+9],  wp[ia*15+10], wp[ia*15+11]);
        u3mat(Un1, wp[(ia+1)*15+12], wp[(ia+1)*15+13], wp[(ia+1)*15+14]);
        float cz, sz, cy, sy, cx, sx;
        sincosf(wp[ia*15+6] * 0.5f, &sz, &cz);
        sincosf(wp[ia*15+7] * 0.5f, &sy, &cy);
        sincosf(wp[ia*15+8] * 0.5f, &sx, &cx);
        // M = X*Y*Z nonzero only at (a,a) and (a,3-a); z_{3-a}==z_a
        float2 acc = make_float2(0.f, 0.f);
#pragma unroll
        for (int a = 0; a < 4; ++a) {
            const float sa = (a == 0 || a == 3) ? 1.f : -1.f;
            const float2 za = (a == 0 || a == 3) ? make_float2(cz, -sz)
                                                 : make_float2(cz,  sz);
            const float daa = fmaf(sa * sx, sy, cx * cy);
            const float oaa = fmaf(sa * sy, cx, -sx * cy);
            float2 Mdiag = make_float2(daa * za.x, daa * za.y);
            float2 Moff  = make_float2(-oaa * za.y, oaa * za.x);
            float2 kpost = cmulf(Uw1[(i >> 1) * 2 + (a >> 1)], Un1[(i & 1) * 2 + (a & 1)]);
            float2 kpreA = cmulf(Uw0[(a >> 1) * 2 + (j >> 1)], Un0[(a & 1) * 2 + (j & 1)]);
            float2 kpreN = cmulf(Uw0[(1 - (a >> 1)) * 2 + (j >> 1)], Un0[(1 - (a & 1)) * 2 + (j & 1)]);
            float2 inner = cmulf(Mdiag, kpreA);
            cmacf(inner, Moff, kpreN);
            cmacf(acc, kpost, inner);
        }
        F = acc;
    }
    mats[g * 16 + k] = F;
}

// ---------------- fused feature + circuit + aggregate kernel --------------
// dense 4x4 conv gate: each thread owns one quad on bits (PW, PN)
template<int PW, int PN>
__device__ __forceinline__ void conv2q(float2* st, const float2* __restrict__ m, int tid)
{
    constexpr int PL = (PW < PN) ? PW : PN;
    constexpr int PH = (PW < PN) ? PN : PW;
    int t1   = ((tid >> PL) << (PL + 1)) | (tid & ((1 << PL) - 1));
    int base = ((t1  >> PH) << (PH + 1)) | (t1  & ((1 << PH) - 1));
    const int i0 = SLOT(base);
    const int i1 = i0 ^ DD(PN);
    const int i2 = i0 ^ DD(PW);
    const int i3 = i2 ^ DD(PN);
    float2 a0 = st[i0], a1 = st[i1], a2 = st[i2], a3 = st[i3];
    float2 n[4];
#pragma unroll
    for (int g = 0; g < 4; ++g) {
        float2 acc = cmulf(m[g*4+0], a0);   // uniform addr -> s_load operands
        cmacf(acc, m[g*4+1], a1);
        cmacf(acc, m[g*4+2], a2);
        cmacf(acc, m[g*4+3], a3);
        n[g] = acc;
    }
    st[i0] = n[0]; st[i1] = n[1]; st[i2] = n[2]; st[i3] = n[3];
}

// cu3 pool gate: control bit PC, target bit PT; touches only ctrl=1 half.
// 256 pairs, one per thread: 2 LDS reads, 16 FMA, 2 writes.
template<int PC, int PT>
__device__ __forceinline__ void pool2q(float2* st, const float2* __restrict__ m, int tid)
{
    constexpr int PL = (PC < PT) ? PC : PT;
    constexpr int PH = (PC < PT) ? PT : PC;
    int t1   = ((tid >> PL) << (PL + 1)) | (tid & ((1 << PL) - 1));
    int base = ((t1  >> PH) << (PH + 1)) | (t1  & ((1 << PH) - 1));
    const int i2 = SLOT(base) ^ DD(PC);     // ctrl=1, tgt=0
    const int i3 = i2 ^ DD(PT);             // ctrl=1, tgt=1
    float2 a2 = st[i2], a3 = st[i3];
    float2 n2 = cmulf(m[10], a2); cmacf(n2, m[11], a3);
    float2 n3 = cmulf(m[14], a2); cmacf(n3, m[15], a3);
    st[i2] = n2; st[i3] = n3;
}

__global__ __launch_bounds__(256) void fused_kernel(
    const float* __restrict__ x,           // (16,22,128)
    const float* __restrict__ proj_w,      // (10,352)
    const float* __restrict__ proj_b,      // (10,)
    const float* __restrict__ freq_scale,  // (10,)
    const float2* __restrict__ mats,       // (23,16)
    const float* __restrict__ wts,         // (113,)
    float* __restrict__ out)               // (16,)
{
    const int s = blockIdx.x;
    const int b = s / WW, w = s % WW;
    const int tid = threadIdx.x;

    __shared__ float2 st[NSTATE];          // 8 KB (also staging for win/feat)
    __shared__ float twre[16], twim[16];
    __shared__ float angs[NQ];
    __shared__ float2 vq[2 * NQ];
    __shared__ float part[4];

    float* win  = (float*)st;          // 352 floats
    float* feat = (float*)st + 512;    // 352 floats

    for (int e = tid; e < CC * 16; e += 256) {
        int c = e >> 4, n = e & 15;
        win[e] = x[b * (CC * 128) + c * 128 + w + n];
    }
    if (tid < 16) {
        float ang = -(float)M_PI * (float)tid * 0.125f;
        float sv, cv; sincosf(ang, &sv, &cv);
        twre[tid] = cv; twim[tid] = sv;
    }
    __syncthreads();

    // DFT features: 176 points (c,k)
    float fval = 0.f, fval2 = 0.f;
    if (tid < CC * NF) {
        int c = tid >> 3, k = tid & 7;
        float re = 0.f, im = 0.f;
#pragma unroll
        for (int n = 0; n < 16; ++n) {
            int mm = (k * n) & 15;
            float xv = win[c * 16 + n];
            re = fmaf(xv, twre[mm], re);
            im = fmaf(xv, twim[mm], im);
        }
        fval  = log1pf(sqrtf(re * re + im * im));
        fval2 = atan2f(im, re) * (float)(1.0 / M_PI);
    }
    __syncthreads();   // done reading win before overwriting region with feat
    if (tid < CC * NF) {
        int c = tid >> 3, k = tid & 7;
        feat[c * 16 + (k << 1)]     = fval;
        feat[c * 16 + (k << 1) + 1] = fval2;
    }
    __syncthreads();

    // projection: 10 dots of length 352 (wave v handles q = v, v+4, v+8)
    {
        int v = tid >> 6, lane = tid & 63;
        for (int q = v; q < NQ; q += 4) {
            float acc = 0.f;
            for (int e = lane; e < FDIM; e += 64) acc += feat[e] * proj_w[q * FDIM + e];
            for (int off = 32; off > 0; off >>= 1) acc += __shfl_xor(acc, off);
            if (lane == 0) angs[q] = tanhf(acc + proj_b[q]) * (float)M_PI;
        }
    }
    __syncthreads();

    if (tid < NQ) {
        float a = angs[tid];
        float bf = freq_scale[tid] * a;
        float ca, sa, cb, sb;
        sincosf(a * 0.5f, &sa, &ca);
        sincosf(bf * 0.5f, &sb, &cb);
        vq[2 * tid]     = make_float2(cb * ca, -sb * sa);
        vq[2 * tid + 1] = make_float2(cb * sa, -sb * ca);
    }
    __syncthreads();

    // product-state init (qubit q <-> bit 9-q), swizzled slots
    for (int idx = tid; idx < NSTATE; idx += 256) {
        float r = 1.f, i = 0.f;
#pragma unroll
        for (int q = 0; q < NQ; ++q) {
            int bit = (idx >> (9 - q)) & 1;
            float2 vv = vq[2 * q + bit];
            float nr = r * vv.x - i * vv.y;
            float ni = r * vv.y + i * vv.x;
            r = nr; i = ni;
        }
        st[SLOT(idx)] = make_float2(r, i);
    }
    __syncthreads();

#define CONV(G, PW, PN) conv2q<PW, PN>(st, mats + (G)*16, tid); __syncthreads();
#define POOL(G, PC, PT) pool2q<PC, PT>(st, mats + (G)*16, tid); __syncthreads();
    // layer 0 conv parity0: qubit pairs (0,1)(2,3)(4,5)(6,7)(8,9)
    CONV(0, 9, 8) CONV(1, 7, 6) CONV(2, 5, 4) CONV(3, 3, 2) CONV(4, 1, 0)
    // layer 0 conv parity1: (1,2)(3,4)(5,6)(7,8)
    CONV(5, 8, 7) CONV(6, 6, 5) CONV(7, 4, 3) CONV(8, 2, 1)
    // layer 0 pool: ctrl->tgt (1->0)(3->2)(5->4)(7->6)(9->8)
    POOL(9, 8, 9) POOL(10, 6, 7) POOL(11, 4, 5) POOL(12, 2, 3) POOL(13, 0, 1)
    // layer 1 conv: (0,2)(4,6) then (2,4)(6,8)
    CONV(14, 9, 7) CONV(15, 5, 3) CONV(16, 7, 5) CONV(17, 3, 1)
    // layer 1 pool: (2->0)(6->4)
    POOL(18, 7, 9) POOL(19, 3, 5)
    // layer 2 conv: (0,4) then (4,8)
    CONV(20, 9, 5) CONV(21, 5, 1)
    // layer 2 pool: (4->0)
    POOL(22, 5, 9)
#undef CONV
#undef POOL

    // measurement: slot bit 9 == logical bit 9 (swizzle only touches bits 0-4)
    float local = 0.f;
    for (int idx = tid; idx < NSTATE; idx += 256) {
        float2 am = st[idx];
        float p = am.x * am.x + am.y * am.y;
        local += (idx < 512) ? p : -p;
    }
    for (int off = 32; off > 0; off >>= 1) local += __shfl_xor(local, off);
    if ((tid & 63) == 0) part[tid >> 6] = local;
    __syncthreads();
    if (tid == 0) {
        float ev = part[0] + part[1] + part[2] + part[3];
        atomicAdd(&out[b], ev * wts[w]);
    }
}

extern "C" void kernel_launch(void* const* d_in, const int* in_sizes, int n_in,
                              void* d_out, int out_size, void* d_ws, size_t ws_size,
                              hipStream_t stream)
{
    const float* x           = (const float*)d_in[0];
    const float* proj_w      = (const float*)d_in[1];
    const float* proj_b      = (const float*)d_in[2];
    const float* freq_scale  = (const float*)d_in[3];
    const float* conv_params = (const float*)d_in[4];
    const float* pool_params = (const float*)d_in[5];
    const float* aggw        = (const float*)d_in[6];
    float* out = (float*)d_out;

    float2* mats = (float2*)d_ws;                 // 23*16 float2
    float* wts   = (float*)d_ws + NGATE * 16 * 2; // 113 floats

    prep_kernel<<<1, 384, 0, stream>>>(conv_params, pool_params, aggw, mats, wts, out);
    fused_kernel<<<NS, 256, 0, stream>>>(x, proj_w, proj_b, freq_scale, mats, wts, out);
}